// Round 1
// baseline (1780.296 us; speedup 1.0000x reference)
//
#include <hip/hip_runtime.h>

#define B_ 32
#define DIM_ 512
#define N_ 2048
#define R_ 64
#define K_ 6
#define EPS_ 2e-8f

#define PAD_ 68  // stride 68 floats: 16B-aligned (272B), bank step 4 -> ~4-way worst on staging writes only

// ---------------- broadcast D/C to per-batch copies ----------------
__global__ __launch_bounds__(256) void k_bcastD(const float* __restrict__ D, float* __restrict__ Db) {
  int i = blockIdx.x * 256 + threadIdx.x;           // B*DIM*R = 1,048,576
  Db[i] = D[i & (DIM_ * R_ - 1)];
}
__global__ __launch_bounds__(256) void k_bcastC(const float* __restrict__ C, float* __restrict__ Cb) {
  int i = blockIdx.x * 256 + threadIdx.x;           // B*R*N = 4,194,304
  Cb[i] = C[i & (R_ * N_ - 1)];
}
__global__ __launch_bounds__(256) void k_zero(float* __restrict__ p) {
  p[blockIdx.x * 256 + threadIdx.x] = 0.f;
}

// ---------------- A[b,r,n] = sum_d relu(x[b,d,n]) * Db[b,d,r] ----------------
// grid (N/256, B, 2): z = d-half. Partials: z=0 -> A, z=1 -> A2 (summed in k_updC).
__global__ __launch_bounds__(256) void k_A(const float* __restrict__ x, const float* __restrict__ Db,
                                           float* __restrict__ A, float* __restrict__ A2) {
  const int b = blockIdx.y;
  const int n = blockIdx.x * 256 + threadIdx.x;
  const int dbase = blockIdx.z * (DIM_ / 2);
  const float* xb = x + (size_t)b * DIM_ * N_ + n;
  const float* Dp = Db + (size_t)b * DIM_ * R_;
  float acc[R_];
#pragma unroll
  for (int r = 0; r < R_; ++r) acc[r] = 0.f;
  __shared__ float ds[32 * R_];
  for (int d0 = dbase; d0 < dbase + DIM_ / 2; d0 += 32) {
    __syncthreads();
    const float4* src = (const float4*)(Dp + (size_t)d0 * R_);
    float4* dst = (float4*)ds;
    dst[threadIdx.x] = src[threadIdx.x];
    dst[threadIdx.x + 256] = src[threadIdx.x + 256];
    __syncthreads();
#pragma unroll 8
    for (int dd = 0; dd < 32; ++dd) {
      float xv = fmaxf(xb[(size_t)(d0 + dd) * N_], 0.f);
      const float4* drow = (const float4*)(ds + dd * R_);
#pragma unroll
      for (int r4 = 0; r4 < 16; ++r4) {
        float4 dv = drow[r4];
        acc[r4 * 4 + 0] = fmaf(xv, dv.x, acc[r4 * 4 + 0]);
        acc[r4 * 4 + 1] = fmaf(xv, dv.y, acc[r4 * 4 + 1]);
        acc[r4 * 4 + 2] = fmaf(xv, dv.z, acc[r4 * 4 + 2]);
        acc[r4 * 4 + 3] = fmaf(xv, dv.w, acc[r4 * 4 + 3]);
      }
    }
  }
  float* Ap = (blockIdx.z == 0 ? A : A2) + (size_t)b * R_ * N_ + n;
#pragma unroll
  for (int r = 0; r < R_; ++r) Ap[(size_t)r * N_] = acc[r];
}

// ---------------- XCt[b,d,r] = sum_n relu(x[b,d,n]) * Cb[b,r,n] ----------------
// grid (DIM/64, B, 2): z = n-half. Partials to XC / X2 (summed in k_updD).
__global__ __launch_bounds__(256) void k_XCt(const float* __restrict__ x, const float* __restrict__ Cb,
                                             float* __restrict__ XC, float* __restrict__ X2) {
  const int b = blockIdx.y;
  const int d0 = blockIdx.x * 64;
  const int nbase = blockIdx.z * (N_ / 2);
  const int t = threadIdx.x;
  const int tr = t & 15;   // r group
  const int td = t >> 4;   // d group
  __shared__ float xs[32 * PAD_];  // [nn][dl]
  __shared__ float cs[32 * PAD_];  // [nn][r]
  float acc[4][4];
#pragma unroll
  for (int i = 0; i < 4; ++i)
#pragma unroll
    for (int j = 0; j < 4; ++j) acc[i][j] = 0.f;
  const float* xb = x + (size_t)b * DIM_ * N_;
  const float* Cp = Cb + (size_t)b * R_ * N_;
  for (int n0 = nbase; n0 < nbase + N_ / 2; n0 += 32) {
    __syncthreads();
#pragma unroll
    for (int i = 0; i < 8; ++i) {
      int idx = t + i * 256;
      int nn = idx & 31;
      int row = idx >> 5;
      xs[nn * PAD_ + row] = fmaxf(xb[(size_t)(d0 + row) * N_ + n0 + nn], 0.f);
      cs[nn * PAD_ + row] = Cp[(size_t)row * N_ + n0 + nn];
    }
    __syncthreads();
#pragma unroll
    for (int nn = 0; nn < 32; ++nn) {
      const float4 a4 = *(const float4*)(xs + nn * PAD_ + td * 4);
      const float4 b4 = *(const float4*)(cs + nn * PAD_ + tr * 4);
      float av[4] = {a4.x, a4.y, a4.z, a4.w};
      float bv[4] = {b4.x, b4.y, b4.z, b4.w};
#pragma unroll
      for (int i = 0; i < 4; ++i)
#pragma unroll
        for (int j = 0; j < 4; ++j) acc[i][j] = fmaf(av[i], bv[j], acc[i][j]);
    }
  }
  float* Xp = (blockIdx.z == 0 ? XC : X2) + (size_t)b * DIM_ * R_;
#pragma unroll
  for (int i = 0; i < 4; ++i) {
    float4 v = make_float4(acc[i][0], acc[i][1], acc[i][2], acc[i][3]);
    *(float4*)(Xp + (size_t)(d0 + td * 4 + i) * R_ + tr * 4) = v;
  }
}

// ---------------- DtD[b,r1,r2] = sum_d Db[b,d,r1]*Db[b,d,r2] (atomic over d-chunks) ----------------
// grid (4, B)
__global__ __launch_bounds__(256) void k_DtD(const float* __restrict__ Db, float* __restrict__ DtD) {
  const int b = blockIdx.y;
  const int t = threadIdx.x;
  const int tr = t & 15, ts = t >> 4;
  const int dstart = blockIdx.x * 128;
  __shared__ float ds[64 * R_];
  float acc[4][4];
#pragma unroll
  for (int i = 0; i < 4; ++i)
#pragma unroll
    for (int j = 0; j < 4; ++j) acc[i][j] = 0.f;
  const float* Dp = Db + (size_t)b * DIM_ * R_;
  for (int d0 = dstart; d0 < dstart + 128; d0 += 64) {
    __syncthreads();
    const float4* src = (const float4*)(Dp + (size_t)d0 * R_);
    float4* dst = (float4*)ds;
#pragma unroll
    for (int i = 0; i < 4; ++i) dst[t + i * 256] = src[t + i * 256];
    __syncthreads();
#pragma unroll 8
    for (int dd = 0; dd < 64; ++dd) {
      const float4 a4 = *(const float4*)(ds + dd * R_ + ts * 4);
      const float4 b4 = *(const float4*)(ds + dd * R_ + tr * 4);
      float av[4] = {a4.x, a4.y, a4.z, a4.w};
      float bv[4] = {b4.x, b4.y, b4.z, b4.w};
#pragma unroll
      for (int i = 0; i < 4; ++i)
#pragma unroll
        for (int j = 0; j < 4; ++j) acc[i][j] = fmaf(av[i], bv[j], acc[i][j]);
    }
  }
  float* P = DtD + (size_t)b * R_ * R_;
#pragma unroll
  for (int i = 0; i < 4; ++i)
#pragma unroll
    for (int j = 0; j < 4; ++j) atomicAdd(&P[(size_t)(ts * 4 + i) * R_ + tr * 4 + j], acc[i][j]);
}

// ---------------- CCt[b,r1,r2] = sum_n Cb[b,r1,n]*Cb[b,r2,n] (atomic over n-chunks) ----------------
// grid (8, B)
__global__ __launch_bounds__(256) void k_CCt(const float* __restrict__ Cb, float* __restrict__ CCt) {
  const int b = blockIdx.y;
  const int t = threadIdx.x;
  const int tr = t & 15, ts = t >> 4;
  const int nstart = blockIdx.x * 256;
  __shared__ float cs[32 * PAD_];  // [nn][r]
  float acc[4][4];
#pragma unroll
  for (int i = 0; i < 4; ++i)
#pragma unroll
    for (int j = 0; j < 4; ++j) acc[i][j] = 0.f;
  const float* Cp = Cb + (size_t)b * R_ * N_;
  for (int n0 = nstart; n0 < nstart + 256; n0 += 32) {
    __syncthreads();
#pragma unroll
    for (int i = 0; i < 8; ++i) {
      int idx = t + i * 256;
      int nn = idx & 31;
      int r = idx >> 5;
      cs[nn * PAD_ + r] = Cp[(size_t)r * N_ + n0 + nn];
    }
    __syncthreads();
#pragma unroll
    for (int nn = 0; nn < 32; ++nn) {
      const float4 a4 = *(const float4*)(cs + nn * PAD_ + ts * 4);
      const float4 b4 = *(const float4*)(cs + nn * PAD_ + tr * 4);
      float av[4] = {a4.x, a4.y, a4.z, a4.w};
      float bv[4] = {b4.x, b4.y, b4.z, b4.w};
#pragma unroll
      for (int i = 0; i < 4; ++i)
#pragma unroll
        for (int j = 0; j < 4; ++j) acc[i][j] = fmaf(av[i], bv[j], acc[i][j]);
    }
  }
  float* P = CCt + (size_t)b * R_ * R_;
#pragma unroll
  for (int i = 0; i < 4; ++i)
#pragma unroll
    for (int j = 0; j < 4; ++j) atomicAdd(&P[(size_t)(ts * 4 + i) * R_ + tr * 4 + j], acc[i][j]);
}

// ---------------- C *= (A+A2) / (DtD @ C + eps), in place, column-local ----------------
// grid (N/256, B)
__global__ __launch_bounds__(256) void k_updC(const float* __restrict__ A, const float* __restrict__ A2,
                                              const float* __restrict__ DtD, float* __restrict__ Cb) {
  const int b = blockIdx.y;
  const int n = blockIdx.x * 256 + threadIdx.x;
  __shared__ float s[R_ * R_];  // DtD (symmetric)
  {
    const float4* src = (const float4*)(DtD + (size_t)b * R_ * R_);
    float4* dst = (float4*)s;
#pragma unroll
    for (int i = 0; i < 4; ++i) dst[threadIdx.x + i * 256] = src[threadIdx.x + i * 256];
  }
  __syncthreads();
  float* Cp = Cb + (size_t)b * R_ * N_ + n;
  const float* Ap = A + (size_t)b * R_ * N_ + n;
  const float* Ap2 = A2 + (size_t)b * R_ * N_ + n;
  float denom[R_];
#pragma unroll
  for (int r = 0; r < R_; ++r) denom[r] = 0.f;
#pragma unroll 8
  for (int rr = 0; rr < R_; ++rr) {
    float c = Cp[(size_t)rr * N_];
    const float4* row = (const float4*)(s + rr * R_);  // DtD[rr][r] == DtD[r][rr]
#pragma unroll
    for (int r4 = 0; r4 < 16; ++r4) {
      float4 v = row[r4];
      denom[r4 * 4 + 0] = fmaf(c, v.x, denom[r4 * 4 + 0]);
      denom[r4 * 4 + 1] = fmaf(c, v.y, denom[r4 * 4 + 1]);
      denom[r4 * 4 + 2] = fmaf(c, v.z, denom[r4 * 4 + 2]);
      denom[r4 * 4 + 3] = fmaf(c, v.w, denom[r4 * 4 + 3]);
    }
  }
#pragma unroll
  for (int r = 0; r < R_; ++r) {
    float c = Cp[(size_t)r * N_];
    float a = Ap[(size_t)r * N_] + Ap2[(size_t)r * N_];
    Cp[(size_t)r * N_] = c * a / (denom[r] + EPS_);
  }
}

// ---------------- D *= (XC+X2) / (D @ CCt + eps), in place, row-tile-local ----------------
// grid (DIM/64, B)
__global__ __launch_bounds__(256) void k_updD(const float* __restrict__ XC, const float* __restrict__ X2,
                                              const float* __restrict__ CCt, float* __restrict__ Db) {
  const int b = blockIdx.y;
  const int d0 = blockIdx.x * 64;
  const int t = threadIdx.x;
  __shared__ float sD[64 * R_];     // D tile, natural [dl][r]
  __shared__ float sC[R_ * PAD_];   // CCt padded [r][rr]
  float* Dp = Db + (size_t)b * DIM_ * R_ + (size_t)d0 * R_;
  const float* Pc = CCt + (size_t)b * R_ * R_;
  {
    const float4* src = (const float4*)Dp;
    float4* dst = (float4*)sD;
#pragma unroll
    for (int i = 0; i < 4; ++i) dst[t + i * 256] = src[t + i * 256];
#pragma unroll
    for (int i = 0; i < 16; ++i) {
      int idx = t + i * 256;
      int r = idx >> 6, c = idx & 63;
      sC[r * PAD_ + c] = Pc[idx];
    }
  }
  __syncthreads();
  const float* Xp = XC + (size_t)b * DIM_ * R_ + (size_t)d0 * R_;
  const float* Xp2 = X2 + (size_t)b * DIM_ * R_ + (size_t)d0 * R_;
  const int r = t & 63;
  const int dg = t >> 6;
  for (int p = 0; p < 16; ++p) {
    const int dl = p * 4 + dg;
    float denom = 0.f;
#pragma unroll
    for (int q = 0; q < 16; ++q) {
      const float4 a4 = *(const float4*)(sD + dl * R_ + q * 4);    // broadcast (uniform dl per wave)
      const float4 b4 = *(const float4*)(sC + r * PAD_ + q * 4);   // CCt[r][rr] (symmetric)
      denom = fmaf(a4.x, b4.x, denom);
      denom = fmaf(a4.y, b4.y, denom);
      denom = fmaf(a4.z, b4.z, denom);
      denom = fmaf(a4.w, b4.w, denom);
    }
    float dv = sD[dl * R_ + r];
    float xv = Xp[(size_t)dl * R_ + r] + Xp2[(size_t)dl * R_ + r];
    Dp[(size_t)dl * R_ + r] = dv * xv / (denom + EPS_);
  }
}

// ---------------- out[b,d,n] = sum_r Db[b,d,r] * Cb[b,r,n] ----------------
// grid (N/64, DIM/64, B)
__global__ __launch_bounds__(256) void k_out(const float* __restrict__ Db, const float* __restrict__ Cb,
                                             float* __restrict__ out) {
  const int b = blockIdx.z;
  const int d0 = blockIdx.y * 64;
  const int n0 = blockIdx.x * 64;
  const int t = threadIdx.x;
  const int tn = t & 15, td = t >> 4;
  __shared__ float sD[64 * PAD_];  // [dl][r] padded
  __shared__ float sC[R_ * 64];    // [r][nn]
  const float* Dp = Db + (size_t)b * DIM_ * R_ + (size_t)d0 * R_;
  const float* Cp = Cb + (size_t)b * R_ * N_;
  {
#pragma unroll
    for (int i = 0; i < 16; ++i) {
      int idx = t + i * 256;
      int rr = idx & 63, dl = idx >> 6;
      sD[dl * PAD_ + rr] = Dp[(size_t)dl * R_ + rr];
    }
#pragma unroll
    for (int i = 0; i < 16; ++i) {
      int idx = t + i * 256;
      int nn = idx & 63, rr = idx >> 6;
      sC[rr * 64 + nn] = Cp[(size_t)rr * N_ + n0 + nn];
    }
  }
  __syncthreads();
  float acc[4][4];
#pragma unroll
  for (int i = 0; i < 4; ++i)
#pragma unroll
    for (int j = 0; j < 4; ++j) acc[i][j] = 0.f;
#pragma unroll 8
  for (int r = 0; r < R_; ++r) {
    float a0 = sD[(td * 4 + 0) * PAD_ + r];
    float a1 = sD[(td * 4 + 1) * PAD_ + r];
    float a2 = sD[(td * 4 + 2) * PAD_ + r];
    float a3 = sD[(td * 4 + 3) * PAD_ + r];
    const float4 b4 = *(const float4*)(sC + r * 64 + tn * 4);
    float bv[4] = {b4.x, b4.y, b4.z, b4.w};
    float av[4] = {a0, a1, a2, a3};
#pragma unroll
    for (int i = 0; i < 4; ++i)
#pragma unroll
      for (int j = 0; j < 4; ++j) acc[i][j] = fmaf(av[i], bv[j], acc[i][j]);
  }
  float* op = out + (size_t)b * DIM_ * N_;
#pragma unroll
  for (int i = 0; i < 4; ++i) {
    float4 v = make_float4(acc[i][0], acc[i][1], acc[i][2], acc[i][3]);
    *(float4*)(op + (size_t)(d0 + td * 4 + i) * N_ + n0 + tn * 4) = v;
  }
}

extern "C" void kernel_launch(void* const* d_in, const int* in_sizes, int n_in,
                              void* d_out, int out_size, void* d_ws, size_t ws_size,
                              hipStream_t stream) {
  const float* x = (const float*)d_in[0];
  const float* D = (const float*)d_in[1];
  const float* C = (const float*)d_in[2];
  float* out = (float*)d_out;

  float* ws = (float*)d_ws;
  float* Db  = ws;                               // 1,048,576
  float* Cb  = Db  + (size_t)B_ * DIM_ * R_;     // 4,194,304
  float* A   = Cb  + (size_t)B_ * R_ * N_;       // 4,194,304
  float* A2  = A   + (size_t)B_ * R_ * N_;       // 4,194,304
  float* XC  = A2  + (size_t)B_ * R_ * N_;       // 1,048,576
  float* X2  = XC  + (size_t)B_ * DIM_ * R_;     // 1,048,576
  float* DtD = X2  + (size_t)B_ * DIM_ * R_;     // 131,072
  float* CCt = DtD + (size_t)B_ * R_ * R_;       // 131,072   (adjacent to DtD)

  k_bcastD<<<dim3(B_ * DIM_ * R_ / 256), 256, 0, stream>>>(D, Db);
  k_bcastC<<<dim3(B_ * R_ * N_ / 256), 256, 0, stream>>>(C, Cb);

  for (int k = 0; k < K_; ++k) {
    k_zero<<<dim3(2 * B_ * R_ * R_ / 256), 256, 0, stream>>>(DtD);  // zeros DtD+CCt
    k_A  <<<dim3(N_ / 256, B_, 2), 256, 0, stream>>>(x, Db, A, A2);
    k_XCt<<<dim3(DIM_ / 64, B_, 2), 256, 0, stream>>>(x, Cb, XC, X2);
    k_DtD<<<dim3(4, B_), 256, 0, stream>>>(Db, DtD);
    k_CCt<<<dim3(8, B_), 256, 0, stream>>>(Cb, CCt);
    k_updC<<<dim3(N_ / 256, B_), 256, 0, stream>>>(A, A2, DtD, Cb);
    k_updD<<<dim3(DIM_ / 64, B_), 256, 0, stream>>>(XC, X2, CCt, Db);
  }
  k_out<<<dim3(N_ / 64, DIM_ / 64, B_), 256, 0, stream>>>(Db, Cb, out);
}

// Round 2
// 867.546 us; speedup vs baseline: 2.0521x; 2.0521x over previous
//
#include <hip/hip_runtime.h>

#define B_ 32
#define DIM_ 512
#define N_ 2048
#define R_ 64
#define K_ 6
#define EPS_ 2e-8f
#define PAD_ 68

typedef short bf16x8 __attribute__((ext_vector_type(8)));
typedef float f32x4 __attribute__((ext_vector_type(4)));

__device__ __forceinline__ unsigned short f2bf(float f) {
  unsigned u = __float_as_uint(f);
  unsigned r = (u + 0x7FFFu + ((u >> 16) & 1u)) >> 16;   // RNE, finite inputs only
  return (unsigned short)r;
}

// ============ one-time: relu(x) -> xbf [b][d][n], xbt [b][n][d] (both bf16) ============
// grid (N/64, DIM/64, B), 256 thr
__global__ __launch_bounds__(256) void k_xprep(const float* __restrict__ x, short* __restrict__ xbf,
                                               short* __restrict__ xbt) {
  const int b = blockIdx.z, d0 = blockIdx.y * 64, n0 = blockIdx.x * 64;
  const int t = threadIdx.x;
  __shared__ short tile[64 * 72];  // [n][d]
  const float* xg = x + (size_t)b * DIM_ * N_ + (size_t)d0 * N_ + n0;
  short* xn = xbf + (size_t)b * DIM_ * N_ + (size_t)d0 * N_ + n0;
#pragma unroll
  for (int i = 0; i < 8; ++i) {
    int idx = i * 512 + t * 2;
    int d = idx >> 6, n = idx & 63;
    float2 v = *(const float2*)(xg + (size_t)d * N_ + n);
    unsigned short b0 = f2bf(fmaxf(v.x, 0.f)), b1 = f2bf(fmaxf(v.y, 0.f));
    *(ushort2*)(xn + (size_t)d * N_ + n) = make_ushort2(b0, b1);
    tile[n * 72 + d] = (short)b0;
    tile[(n + 1) * 72 + d] = (short)b1;
  }
  __syncthreads();
  short* xt = xbt + (size_t)b * N_ * DIM_ + (size_t)n0 * DIM_ + d0;
#pragma unroll
  for (int i = 0; i < 2; ++i) {
    int idx = i * 256 + t;
    int n = idx >> 3, c = idx & 7;
    *(int4*)(xt + (size_t)n * DIM_ + c * 8) = *(const int4*)(tile + n * 72 + c * 8);
  }
}

// ============ broadcast D -> Db f32, Dbf [d][r], Dbt [r][d] ============ grid (8, B)
__global__ __launch_bounds__(256) void k_bcastD(const float* __restrict__ D, float* __restrict__ Db,
                                                short* __restrict__ Dbf, short* __restrict__ Dbt) {
  const int b = blockIdx.y, d0 = blockIdx.x * 64, t = threadIdx.x;
  __shared__ short tile[64 * 72];  // [r][d]
  const float* g = D + (size_t)d0 * R_;
  float* fo = Db + (size_t)b * DIM_ * R_ + (size_t)d0 * R_;
  short* no = Dbf + (size_t)b * DIM_ * R_ + (size_t)d0 * R_;
#pragma unroll
  for (int i = 0; i < 8; ++i) {
    int idx = i * 512 + t * 2;
    int d = idx >> 6, r = idx & 63;
    float2 v = *(const float2*)(g + (size_t)d * R_ + r);
    *(float2*)(fo + (size_t)d * R_ + r) = v;
    unsigned short b0 = f2bf(v.x), b1 = f2bf(v.y);
    *(ushort2*)(no + (size_t)d * R_ + r) = make_ushort2(b0, b1);
    tile[r * 72 + d] = (short)b0;
    tile[(r + 1) * 72 + d] = (short)b1;
  }
  __syncthreads();
  short* to = Dbt + (size_t)b * R_ * DIM_ + d0;
#pragma unroll
  for (int i = 0; i < 2; ++i) {
    int idx = i * 256 + t;
    int r = idx >> 3, c = idx & 7;
    *(int4*)(to + (size_t)r * DIM_ + c * 8) = *(const int4*)(tile + r * 72 + c * 8);
  }
}

// ============ broadcast C -> Cb f32, Cbf [r][n], Cbt [n][r] ============ grid (32, B)
__global__ __launch_bounds__(256) void k_bcastC(const float* __restrict__ C, float* __restrict__ Cb,
                                                short* __restrict__ Cbf, short* __restrict__ Cbt) {
  const int b = blockIdx.y, n0 = blockIdx.x * 64, t = threadIdx.x;
  __shared__ short tile[64 * 72];  // [n][r]
  const float* g = C + n0;
  float* fo = Cb + (size_t)b * R_ * N_ + n0;
  short* no = Cbf + (size_t)b * R_ * N_ + n0;
#pragma unroll
  for (int i = 0; i < 8; ++i) {
    int idx = i * 512 + t * 2;
    int r = idx >> 6, nn = idx & 63;
    float2 v = *(const float2*)(g + (size_t)r * N_ + nn);
    *(float2*)(fo + (size_t)r * N_ + nn) = v;
    unsigned short b0 = f2bf(v.x), b1 = f2bf(v.y);
    *(ushort2*)(no + (size_t)r * N_ + nn) = make_ushort2(b0, b1);
    tile[nn * 72 + r] = (short)b0;
    tile[(nn + 1) * 72 + r] = (short)b1;
  }
  __syncthreads();
  short* to = Cbt + (size_t)b * N_ * R_ + (size_t)n0 * R_;
#pragma unroll
  for (int i = 0; i < 2; ++i) {
    int idx = i * 256 + t;
    int nn = idx >> 3, c = idx & 7;
    *(int4*)(to + (size_t)nn * R_ + c * 8) = *(const int4*)(tile + nn * 72 + c * 8);
  }
}

// ============ A[b,r,n] = sum_d Dt[r,d]*xt[n,d]  (MFMA, ksplit2 -> A/A2) ============
// grid (N/256, B, 2), 256 thr
__global__ __launch_bounds__(256, 2) void k_A(const short* __restrict__ xbt, const short* __restrict__ Dbt,
                                              float* __restrict__ A, float* __restrict__ A2) {
  const int b = blockIdx.y, n0 = blockIdx.x * 256, dbase = blockIdx.z * 256;
  const int t = threadIdx.x;
  const int w = t >> 6, ln = t & 15, lg = (t & 63) >> 4;
  __shared__ short xs[256 * 40];  // [n][d-chunk] pitch 40
  __shared__ short ds[64 * 40];   // [r][d-chunk]
  f32x4 acc[4][4];
#pragma unroll
  for (int mt = 0; mt < 4; ++mt)
#pragma unroll
    for (int nt = 0; nt < 4; ++nt) acc[mt][nt] = (f32x4){0.f, 0.f, 0.f, 0.f};
  const short* xg = xbt + (size_t)b * N_ * DIM_ + (size_t)(n0 + t) * DIM_ + dbase;
  const short* dg = Dbt + (size_t)b * R_ * DIM_ + (size_t)(t & 63) * DIM_ + dbase + (t >> 6) * 8;
  for (int cc = 0; cc < 8; ++cc) {
    __syncthreads();
    const int4* gx = (const int4*)(xg + cc * 32);
    int4 v0 = gx[0], v1 = gx[1], v2 = gx[2], v3 = gx[3];
    int4 dv = *(const int4*)(dg + cc * 32);
    int4* lx = (int4*)(xs + t * 40);
    lx[0] = v0; lx[1] = v1; lx[2] = v2; lx[3] = v3;
    *(int4*)(ds + (t & 63) * 40 + (t >> 6) * 8) = dv;
    __syncthreads();
    bf16x8 af[4], bfv[4];
#pragma unroll
    for (int mt = 0; mt < 4; ++mt) af[mt] = *(const bf16x8*)(ds + (mt * 16 + ln) * 40 + lg * 8);
#pragma unroll
    for (int nt = 0; nt < 4; ++nt) bfv[nt] = *(const bf16x8*)(xs + (w * 64 + nt * 16 + ln) * 40 + lg * 8);
#pragma unroll
    for (int mt = 0; mt < 4; ++mt)
#pragma unroll
      for (int nt = 0; nt < 4; ++nt)
        acc[mt][nt] = __builtin_amdgcn_mfma_f32_16x16x32_bf16(af[mt], bfv[nt], acc[mt][nt], 0, 0, 0);
  }
  float* Ap = (blockIdx.z == 0 ? A : A2) + (size_t)b * R_ * N_;
#pragma unroll
  for (int mt = 0; mt < 4; ++mt)
#pragma unroll
    for (int nt = 0; nt < 4; ++nt) {
      int n = n0 + w * 64 + nt * 16 + ln;
#pragma unroll
      for (int q = 0; q < 4; ++q)
        Ap[(size_t)(mt * 16 + lg * 4 + q) * N_ + n] = acc[mt][nt][q];
    }
}

// ============ XC[b,d,r] = sum_n xbf[d,n]*Cbf[r,n]  (MFMA, ksplit2 -> XC/X2) ============
// grid (DIM/64, B, 2), 256 thr
__global__ __launch_bounds__(256, 2) void k_XCt(const short* __restrict__ xbf, const short* __restrict__ Cbf,
                                                float* __restrict__ XC, float* __restrict__ X2) {
  const int b = blockIdx.y, d0 = blockIdx.x * 64, nbase = blockIdx.z * 1024;
  const int t = threadIdx.x;
  const int w = t >> 6, ln = t & 15, lg = (t & 63) >> 4;
  __shared__ short xs[64 * 40];  // [d][n-chunk]
  __shared__ short cs[64 * 40];  // [r][n-chunk]
  f32x4 acc[4];
#pragma unroll
  for (int nt = 0; nt < 4; ++nt) acc[nt] = (f32x4){0.f, 0.f, 0.f, 0.f};
  const short* xg = xbf + (size_t)b * DIM_ * N_ + (size_t)(d0 + (t & 63)) * N_ + nbase + (t >> 6) * 8;
  const short* cg = Cbf + (size_t)b * R_ * N_ + (size_t)(t & 63) * N_ + nbase + (t >> 6) * 8;
  for (int cc = 0; cc < 32; ++cc) {
    __syncthreads();
    int4 xv = *(const int4*)(xg + cc * 32);
    int4 cv = *(const int4*)(cg + cc * 32);
    *(int4*)(xs + (t & 63) * 40 + (t >> 6) * 8) = xv;
    *(int4*)(cs + (t & 63) * 40 + (t >> 6) * 8) = cv;
    __syncthreads();
    bf16x8 a = *(const bf16x8*)(xs + (w * 16 + ln) * 40 + lg * 8);
#pragma unroll
    for (int nt = 0; nt < 4; ++nt) {
      bf16x8 bb = *(const bf16x8*)(cs + (nt * 16 + ln) * 40 + lg * 8);
      acc[nt] = __builtin_amdgcn_mfma_f32_16x16x32_bf16(a, bb, acc[nt], 0, 0, 0);
    }
  }
  float* Xp = (blockIdx.z == 0 ? XC : X2) + (size_t)b * DIM_ * R_;
#pragma unroll
  for (int nt = 0; nt < 4; ++nt)
#pragma unroll
    for (int q = 0; q < 4; ++q)
      Xp[(size_t)(d0 + w * 16 + lg * 4 + q) * R_ + nt * 16 + ln] = acc[nt][q];
}

// ============ gram: blockIdx.x==0 -> DtD = Dt@DtT (K=512); ==1 -> CCt = C@Ct (K=2048) ============
// grid (2, B), 256 thr
__global__ __launch_bounds__(256) void k_gram(const short* __restrict__ Dbt, const short* __restrict__ Cbf,
                                              float* __restrict__ DtD, float* __restrict__ CCt) {
  const int b = blockIdx.y, which = blockIdx.x;
  const int t = threadIdx.x;
  const int w = t >> 6, ln = t & 15, lg = (t & 63) >> 4;
  __shared__ short s[64 * 40];
  const short* src;
  size_t stride;
  int nch;
  float* out;
  if (which == 0) {
    src = Dbt + (size_t)b * R_ * DIM_; stride = DIM_; nch = 16; out = DtD + (size_t)b * R_ * R_;
  } else {
    src = Cbf + (size_t)b * R_ * N_; stride = N_; nch = 64; out = CCt + (size_t)b * R_ * R_;
  }
  const short* g = src + (size_t)(t & 63) * stride + (t >> 6) * 8;
  f32x4 acc[4];
#pragma unroll
  for (int nt = 0; nt < 4; ++nt) acc[nt] = (f32x4){0.f, 0.f, 0.f, 0.f};
  for (int cc = 0; cc < nch; ++cc) {
    __syncthreads();
    *(int4*)(s + (t & 63) * 40 + (t >> 6) * 8) = *(const int4*)(g + cc * 32);
    __syncthreads();
    bf16x8 a = *(const bf16x8*)(s + (w * 16 + ln) * 40 + lg * 8);
#pragma unroll
    for (int nt = 0; nt < 4; ++nt) {
      bf16x8 bb = *(const bf16x8*)(s + (nt * 16 + ln) * 40 + lg * 8);
      acc[nt] = __builtin_amdgcn_mfma_f32_16x16x32_bf16(a, bb, acc[nt], 0, 0, 0);
    }
  }
#pragma unroll
  for (int nt = 0; nt < 4; ++nt)
#pragma unroll
    for (int q = 0; q < 4; ++q)
      out[(size_t)(w * 16 + lg * 4 + q) * R_ + nt * 16 + ln] = acc[nt][q];
}

// ============ C *= (A+A2)/(DtD@C + eps); emit f32 + bf16 mirrors ============ grid (N/256, B)
__global__ __launch_bounds__(256) void k_updC(const float* __restrict__ A, const float* __restrict__ A2,
                                              const float* __restrict__ DtD, float* __restrict__ Cb,
                                              short* __restrict__ Cbf, short* __restrict__ Cbt) {
  const int b = blockIdx.y;
  const int n = blockIdx.x * 256 + threadIdx.x;
  __shared__ float s[R_ * R_];
  {
    const float4* src = (const float4*)(DtD + (size_t)b * R_ * R_);
    float4* dst = (float4*)s;
#pragma unroll
    for (int i = 0; i < 4; ++i) dst[threadIdx.x + i * 256] = src[threadIdx.x + i * 256];
  }
  __syncthreads();
  float* Cp = Cb + (size_t)b * R_ * N_ + n;
  const float* Ap = A + (size_t)b * R_ * N_ + n;
  const float* Ap2 = A2 + (size_t)b * R_ * N_ + n;
  float denom[R_];
#pragma unroll
  for (int r = 0; r < R_; ++r) denom[r] = 0.f;
#pragma unroll 8
  for (int rr = 0; rr < R_; ++rr) {
    float c = Cp[(size_t)rr * N_];
    const float4* row = (const float4*)(s + rr * R_);  // DtD symmetric
#pragma unroll
    for (int r4 = 0; r4 < 16; ++r4) {
      float4 v = row[r4];
      denom[r4 * 4 + 0] = fmaf(c, v.x, denom[r4 * 4 + 0]);
      denom[r4 * 4 + 1] = fmaf(c, v.y, denom[r4 * 4 + 1]);
      denom[r4 * 4 + 2] = fmaf(c, v.z, denom[r4 * 4 + 2]);
      denom[r4 * 4 + 3] = fmaf(c, v.w, denom[r4 * 4 + 3]);
    }
  }
  short* nf = Cbf + (size_t)b * R_ * N_ + n;
  unsigned* tf = (unsigned*)(Cbt + (size_t)b * N_ * R_ + (size_t)n * R_);
#pragma unroll
  for (int r = 0; r < R_; r += 2) {
    float c0 = Cp[(size_t)r * N_], c1 = Cp[(size_t)(r + 1) * N_];
    float v0 = c0 * (Ap[(size_t)r * N_] + Ap2[(size_t)r * N_]) / (denom[r] + EPS_);
    float v1 = c1 * (Ap[(size_t)(r + 1) * N_] + Ap2[(size_t)(r + 1) * N_]) / (denom[r + 1] + EPS_);
    Cp[(size_t)r * N_] = v0;
    Cp[(size_t)(r + 1) * N_] = v1;
    unsigned b0 = f2bf(v0), b1 = f2bf(v1);
    nf[(size_t)r * N_] = (short)b0;
    nf[(size_t)(r + 1) * N_] = (short)b1;
    tf[r >> 1] = b0 | (b1 << 16);
  }
}

// ============ D *= (XC+X2)/(D@CCt + eps); emit f32 + bf16 mirrors ============ grid (DIM/64, B)
__global__ __launch_bounds__(256) void k_updD(const float* __restrict__ XC, const float* __restrict__ X2,
                                              const float* __restrict__ CCt, float* __restrict__ Db,
                                              short* __restrict__ Dbf, short* __restrict__ Dbt) {
  const int b = blockIdx.y;
  const int d0 = blockIdx.x * 64;
  const int t = threadIdx.x;
  __shared__ float sD[64 * R_];
  __shared__ float sC[R_ * PAD_];
  float* Dp = Db + (size_t)b * DIM_ * R_ + (size_t)d0 * R_;
  const float* Pc = CCt + (size_t)b * R_ * R_;
  {
    const float4* src = (const float4*)Dp;
    float4* dst = (float4*)sD;
#pragma unroll
    for (int i = 0; i < 4; ++i) dst[t + i * 256] = src[t + i * 256];
#pragma unroll
    for (int i = 0; i < 16; ++i) {
      int idx = t + i * 256;
      int r = idx >> 6, c = idx & 63;
      sC[r * PAD_ + c] = Pc[idx];
    }
  }
  __syncthreads();
  const float* Xp = XC + (size_t)b * DIM_ * R_ + (size_t)d0 * R_;
  const float* Xp2 = X2 + (size_t)b * DIM_ * R_ + (size_t)d0 * R_;
  short* nf = Dbf + (size_t)b * DIM_ * R_ + (size_t)d0 * R_;
  short* tfD = Dbt + (size_t)b * R_ * DIM_ + d0;
  const int r = t & 63;
  const int dg = t >> 6;
  for (int p = 0; p < 16; ++p) {
    const int dl = p * 4 + dg;
    float denom = 0.f;
#pragma unroll
    for (int q = 0; q < 16; ++q) {
      const float4 a4 = *(const float4*)(sD + dl * R_ + q * 4);
      const float4 b4 = *(const float4*)(sC + r * PAD_ + q * 4);
      denom = fmaf(a4.x, b4.x, denom);
      denom = fmaf(a4.y, b4.y, denom);
      denom = fmaf(a4.z, b4.z, denom);
      denom = fmaf(a4.w, b4.w, denom);
    }
    float dv = sD[dl * R_ + r];
    float xv = Xp[(size_t)dl * R_ + r] + Xp2[(size_t)dl * R_ + r];
    float nv = dv * xv / (denom + EPS_);
    Dp[(size_t)dl * R_ + r] = nv;
    unsigned short bb = f2bf(nv);
    nf[(size_t)dl * R_ + r] = (short)bb;
    tfD[(size_t)r * DIM_ + dl] = (short)bb;  // scattered 2B; L2 merges lines
  }
}

// ============ out[b,d,n] = sum_r Dbf[d,r]*Cbt[n,r]  (MFMA, K=64) ============
// grid (N/128, DIM/64, B), 256 thr
__global__ __launch_bounds__(256) void k_out(const short* __restrict__ Dbf, const short* __restrict__ Cbt,
                                             float* __restrict__ out) {
  const int b = blockIdx.z, d0 = blockIdx.y * 64, n0 = blockIdx.x * 128;
  const int t = threadIdx.x;
  const int w = t >> 6, ln = t & 15, lg = (t & 63) >> 4;
  __shared__ short ct[128 * 72];  // [n][r]
  __shared__ short dn[64 * 72];   // [d][r]
#pragma unroll
  for (int i = 0; i < 4; ++i) {
    int idx = i * 256 + t;
    int row = idx >> 3, c = idx & 7;
    *(int4*)(ct + row * 72 + c * 8) =
        *(const int4*)(Cbt + (size_t)b * N_ * R_ + (size_t)(n0 + row) * R_ + c * 8);
  }
#pragma unroll
  for (int i = 0; i < 2; ++i) {
    int idx = i * 256 + t;
    int row = idx >> 3, c = idx & 7;
    *(int4*)(dn + row * 72 + c * 8) =
        *(const int4*)(Dbf + (size_t)b * DIM_ * R_ + (size_t)(d0 + row) * R_ + c * 8);
  }
  __syncthreads();
  f32x4 acc[4][2];
#pragma unroll
  for (int mt = 0; mt < 4; ++mt)
#pragma unroll
    for (int nt = 0; nt < 2; ++nt) acc[mt][nt] = (f32x4){0.f, 0.f, 0.f, 0.f};
#pragma unroll
  for (int kc = 0; kc < 2; ++kc) {
    bf16x8 a[4], bb[2];
#pragma unroll
    for (int mt = 0; mt < 4; ++mt) a[mt] = *(const bf16x8*)(dn + (mt * 16 + ln) * 72 + kc * 32 + lg * 8);
#pragma unroll
    for (int nt = 0; nt < 2; ++nt)
      bb[nt] = *(const bf16x8*)(ct + (w * 32 + nt * 16 + ln) * 72 + kc * 32 + lg * 8);
#pragma unroll
    for (int mt = 0; mt < 4; ++mt)
#pragma unroll
      for (int nt = 0; nt < 2; ++nt)
        acc[mt][nt] = __builtin_amdgcn_mfma_f32_16x16x32_bf16(a[mt], bb[nt], acc[mt][nt], 0, 0, 0);
  }
  float* op = out + (size_t)b * DIM_ * N_;
#pragma unroll
  for (int mt = 0; mt < 4; ++mt)
#pragma unroll
    for (int nt = 0; nt < 2; ++nt) {
      int n = n0 + w * 32 + nt * 16 + ln;
#pragma unroll
      for (int q = 0; q < 4; ++q)
        op[(size_t)(d0 + mt * 16 + lg * 4 + q) * N_ + n] = acc[mt][nt][q];
    }
}

extern "C" void kernel_launch(void* const* d_in, const int* in_sizes, int n_in,
                              void* d_out, int out_size, void* d_ws, size_t ws_size,
                              hipStream_t stream) {
  const float* x = (const float*)d_in[0];
  const float* D = (const float*)d_in[1];
  const float* C = (const float*)d_in[2];
  float* out = (float*)d_out;

  // ---- workspace layout (ws: ~118.5 MB) ----
  char* w = (char*)d_ws;
  short* xbf = (short*)(w);                  // 67,108,864  x bf16 [b][d][n]
  short* Cbf = (short*)(w + 67108864);       //  8,388,608  C bf16 [b][r][n]
  short* Cbt = (short*)(w + 75497472);       //  8,388,608  C^T bf16 [b][n][r]
  short* Dbf = (short*)(w + 83886080);       //  2,097,152  D bf16 [b][d][r]
  short* Dbt = (short*)(w + 85983232);       //  2,097,152  D^T bf16 [b][r][d]
  float* A   = (float*)(w + 88080384);       // 16,777,216  Dt@x partial (d 0..255)
  float* XC  = (float*)(w + 104857600);      //  4,194,304  x@Ct partial (n 0..1023)
  float* X2  = (float*)(w + 109051904);      //  4,194,304  x@Ct partial (n 1024..)
  float* Db  = (float*)(w + 113246208);      //  4,194,304  D f32 state
  float* DtD = (float*)(w + 117440512);      //    524,288
  float* CCt = (float*)(w + 117964800);      //    524,288
  // ---- overlay in d_out (128 MB; k_out reads none of these, overwrites all at end) ----
  char* o = (char*)d_out;
  short* xbt = (short*)o;                    // 67,108,864  x^T bf16 [b][n][d]
  float* A2  = (float*)(o + 67108864);       // 16,777,216  Dt@x partial (d 256..511)
  float* Cb  = (float*)(o + 83886080);       // 16,777,216  C f32 state

  k_xprep<<<dim3(N_ / 64, DIM_ / 64, B_), 256, 0, stream>>>(x, xbf, xbt);
  k_bcastD<<<dim3(DIM_ / 64, B_), 256, 0, stream>>>(D, Db, Dbf, Dbt);
  k_bcastC<<<dim3(N_ / 64, B_), 256, 0, stream>>>(C, Cb, Cbf, Cbt);

  for (int k = 0; k < K_; ++k) {
    k_A<<<dim3(N_ / 256, B_, 2), 256, 0, stream>>>(xbt, Dbt, A, A2);
    k_XCt<<<dim3(DIM_ / 64, B_, 2), 256, 0, stream>>>(xbf, Cbf, XC, X2);
    k_gram<<<dim3(2, B_), 256, 0, stream>>>(Dbt, Cbf, DtD, CCt);
    k_updC<<<dim3(N_ / 256, B_), 256, 0, stream>>>(A, A2, DtD, Cb, Cbf, Cbt);
    k_updD<<<dim3(DIM_ / 64, B_), 256, 0, stream>>>(XC, X2, CCt, Db, Dbf, Dbt);
  }
  k_out<<<dim3(N_ / 128, DIM_ / 64, B_), 256, 0, stream>>>(Dbf, Cbt, out);
}

// Round 3
// 489.080 us; speedup vs baseline: 3.6401x; 1.7738x over previous
//
#include <hip/hip_runtime.h>

#define B_ 32
#define DIM_ 512
#define N_ 2048
#define R_ 64
#define K_ 6
#define EPS_ 2e-8f

typedef short bf16x8 __attribute__((ext_vector_type(8)));
typedef float f32x4 __attribute__((ext_vector_type(4)));

__device__ __forceinline__ unsigned short f2bf(float f) {
  unsigned u = __float_as_uint(f);
  unsigned r = (u + 0x7FFFu + ((u >> 16) & 1u)) >> 16;  // RNE, finite nonneg inputs
  return (unsigned short)r;
}

// ============ one-time: relu(x) -> xbf [b][d][n], xbt [b][n][d] (both bf16) ============
// grid (N/64, DIM/64, B), 256 thr
__global__ __launch_bounds__(256) void k_xprep(const float* __restrict__ x, short* __restrict__ xbf,
                                               short* __restrict__ xbt) {
  const int b = blockIdx.z, d0 = blockIdx.y * 64, n0 = blockIdx.x * 64;
  const int t = threadIdx.x;
  __shared__ short tile[64 * 72];  // [n][d]
  const float* xg = x + (size_t)b * DIM_ * N_ + (size_t)d0 * N_ + n0;
  short* xn = xbf + (size_t)b * DIM_ * N_ + (size_t)d0 * N_ + n0;
#pragma unroll
  for (int i = 0; i < 8; ++i) {
    int idx = i * 512 + t * 2;
    int d = idx >> 6, n = idx & 63;
    float2 v = *(const float2*)(xg + (size_t)d * N_ + n);
    unsigned short b0 = f2bf(fmaxf(v.x, 0.f)), b1 = f2bf(fmaxf(v.y, 0.f));
    *(ushort2*)(xn + (size_t)d * N_ + n) = make_ushort2(b0, b1);
    tile[n * 72 + d] = (short)b0;
    tile[(n + 1) * 72 + d] = (short)b1;
  }
  __syncthreads();
  short* xt = xbt + (size_t)b * N_ * DIM_ + (size_t)n0 * DIM_ + d0;
#pragma unroll
  for (int i = 0; i < 2; ++i) {
    int idx = i * 256 + t;
    int n = idx >> 3, c = idx & 7;
    *(int4*)(xt + (size_t)n * DIM_ + c * 8) = *(const int4*)(tile + n * 72 + c * 8);
  }
}

// ============ bcastD: D -> Db0 f32, Dbf0 [d][r], Dbt0 [r][d], DtD_part[0] ============
// grid (8, B), 256 thr
__global__ __launch_bounds__(256) void k_bcastD(const float* __restrict__ D, float* __restrict__ Db,
                                                short* __restrict__ Dbf, short* __restrict__ Dbt,
                                                float* __restrict__ DtDp) {
  const int b = blockIdx.y, d0 = blockIdx.x * 64, t = threadIdx.x;
  const int w = t >> 6, ln = t & 15, lg = (t & 63) >> 4;
  __shared__ short dtt[64 * 72];  // [r][dl]
#pragma unroll
  for (int j = 0; j < 16; ++j) {
    int idx = t + j * 256;
    int d = idx >> 6, r = idx & 63;
    float v = D[(size_t)(d0 + d) * R_ + r];
    Db[((size_t)b * DIM_ + d0 + d) * R_ + r] = v;
    unsigned short h = f2bf(v);
    Dbf[((size_t)b * DIM_ + d0 + d) * R_ + r] = (short)h;
    dtt[r * 72 + d] = (short)h;
  }
  __syncthreads();
#pragma unroll
  for (int j = 0; j < 2; ++j) {
    int i = t + j * 256;
    int row = i >> 3, c = i & 7;
    *(int4*)(Dbt + ((size_t)b * R_ + row) * DIM_ + d0 + c * 8) = *(const int4*)(dtt + row * 72 + c * 8);
  }
  f32x4 g[4];
#pragma unroll
  for (int nt = 0; nt < 4; ++nt) g[nt] = (f32x4){0.f, 0.f, 0.f, 0.f};
#pragma unroll
  for (int kc = 0; kc < 2; ++kc) {
    bf16x8 a = *(const bf16x8*)(dtt + (w * 16 + ln) * 72 + kc * 32 + lg * 8);
#pragma unroll
    for (int nt = 0; nt < 4; ++nt) {
      bf16x8 bb = *(const bf16x8*)(dtt + (nt * 16 + ln) * 72 + kc * 32 + lg * 8);
      g[nt] = __builtin_amdgcn_mfma_f32_16x16x32_bf16(a, bb, g[nt], 0, 0, 0);
    }
  }
  float* Po = DtDp + ((size_t)b * 8 + blockIdx.x) * 4096;
#pragma unroll
  for (int nt = 0; nt < 4; ++nt)
#pragma unroll
    for (int q = 0; q < 4; ++q) Po[(w * 16 + lg * 4 + q) * 64 + nt * 16 + ln] = g[nt][q];
}

// ============ bcastC: C -> Cb0 f32, Cbf0 [r][n], Cbt0 [n][r], CCt_part[0] ============
// grid (16, B), 256 thr
__global__ __launch_bounds__(256) void k_bcastC(const float* __restrict__ C, float* __restrict__ Cb,
                                                short* __restrict__ Cbf, short* __restrict__ Cbt,
                                                float* __restrict__ CCtp) {
  const int b = blockIdx.y, ns = blockIdx.x * 128, t = threadIdx.x;
  const int w = t >> 6, ln = t & 15, lg = (t & 63) >> 4;
  __shared__ short crt[64 * 136];  // [r][n]
  __shared__ short ctt[128 * 72];  // [n][r]
#pragma unroll
  for (int j = 0; j < 32; ++j) {
    int idx = t + j * 256;
    int r = idx >> 7, n = idx & 127;
    float v = C[(size_t)r * N_ + ns + n];
    Cb[((size_t)b * R_ + r) * N_ + ns + n] = v;
    unsigned short h = f2bf(v);
    Cbf[((size_t)b * R_ + r) * N_ + ns + n] = (short)h;
    crt[r * 136 + n] = (short)h;
    ctt[n * 72 + r] = (short)h;
  }
  __syncthreads();
#pragma unroll
  for (int j = 0; j < 4; ++j) {
    int i = t + j * 256;
    int row = i >> 3, c = i & 7;
    *(int4*)(Cbt + ((size_t)b * N_ + ns + row) * R_ + c * 8) = *(const int4*)(ctt + row * 72 + c * 8);
  }
  f32x4 g[4];
#pragma unroll
  for (int nt = 0; nt < 4; ++nt) g[nt] = (f32x4){0.f, 0.f, 0.f, 0.f};
#pragma unroll
  for (int kc = 0; kc < 4; ++kc) {
    bf16x8 a = *(const bf16x8*)(crt + (w * 16 + ln) * 136 + kc * 32 + lg * 8);
#pragma unroll
    for (int nt = 0; nt < 4; ++nt) {
      bf16x8 bb = *(const bf16x8*)(crt + (nt * 16 + ln) * 136 + kc * 32 + lg * 8);
      g[nt] = __builtin_amdgcn_mfma_f32_16x16x32_bf16(a, bb, g[nt], 0, 0, 0);
    }
  }
  float* Po = CCtp + ((size_t)b * 16 + blockIdx.x) * 4096;
#pragma unroll
  for (int nt = 0; nt < 4; ++nt)
#pragma unroll
    for (int q = 0; q < 4; ++q) Po[(w * 16 + lg * 4 + q) * 64 + nt * 16 + ln] = g[nt][q];
}

// ============ fused: A = Dt@x (K=512), denom = DtD@C (K=64), C update, mirrors, CCt partial ============
// grid (N/128, B), 256 thr
__global__ __launch_bounds__(256, 2) void k_AC(
    const short* __restrict__ xbt, const short* __restrict__ Dbt_o, const float* __restrict__ Cb_o,
    const short* __restrict__ Cbt_o, const float* __restrict__ DtDp_o, float* __restrict__ Cb_n,
    short* __restrict__ Cbf_n, short* __restrict__ Cbt_n, float* __restrict__ CCtp_n) {
  const int b = blockIdx.y, ns = blockIdx.x * 128;
  const int t = threadIdx.x;
  const int w = t >> 6, ln = t & 15, lg = (t & 63) >> 4;
  __shared__ short xs[128 * 40];  // [n][d-chunk]
  __shared__ short ds[64 * 40];   // [r][d-chunk]
  __shared__ short dtd[64 * 72];  // bf16 DtD
  __shared__ short crt[64 * 136]; // C_new [r][n]
  __shared__ short ctt[128 * 72]; // C_new [n][r]
  // DtD partial sum -> bf16 LDS (read before use guarded by main-loop barriers)
  {
    const float* P = DtDp_o + (size_t)b * 8 * 4096;
#pragma unroll
    for (int j = 0; j < 16; ++j) {
      int idx = t + j * 256;
      float s = 0.f;
#pragma unroll
      for (int ss = 0; ss < 8; ++ss) s += P[ss * 4096 + idx];
      dtd[(idx >> 6) * 72 + (idx & 63)] = (short)f2bf(s);
    }
  }
  f32x4 acc[4][2];
#pragma unroll
  for (int mt = 0; mt < 4; ++mt)
#pragma unroll
    for (int nt = 0; nt < 2; ++nt) acc[mt][nt] = (f32x4){0.f, 0.f, 0.f, 0.f};
  for (int kc = 0; kc < 16; ++kc) {
    const int d0 = kc * 32;
    __syncthreads();
    int4 xv[2], dv;
#pragma unroll
    for (int j = 0; j < 2; ++j) {
      int i = t + j * 256;
      int row = i >> 2, c = i & 3;
      xv[j] = *(const int4*)(xbt + ((size_t)b * N_ + ns + row) * DIM_ + d0 + c * 8);
    }
    {
      int row = t >> 2, c = t & 3;
      dv = *(const int4*)(Dbt_o + ((size_t)b * R_ + row) * DIM_ + d0 + c * 8);
    }
#pragma unroll
    for (int j = 0; j < 2; ++j) {
      int i = t + j * 256;
      int row = i >> 2, c = i & 3;
      *(int4*)(xs + row * 40 + c * 8) = xv[j];
    }
    {
      int row = t >> 2, c = t & 3;
      *(int4*)(ds + row * 40 + c * 8) = dv;
    }
    __syncthreads();
    bf16x8 af[4], bfv[2];
#pragma unroll
    for (int mt = 0; mt < 4; ++mt) af[mt] = *(const bf16x8*)(ds + (mt * 16 + ln) * 40 + lg * 8);
#pragma unroll
    for (int nt = 0; nt < 2; ++nt) bfv[nt] = *(const bf16x8*)(xs + (w * 32 + nt * 16 + ln) * 40 + lg * 8);
#pragma unroll
    for (int mt = 0; mt < 4; ++mt)
#pragma unroll
      for (int nt = 0; nt < 2; ++nt)
        acc[mt][nt] = __builtin_amdgcn_mfma_f32_16x16x32_bf16(af[mt], bfv[nt], acc[mt][nt], 0, 0, 0);
  }
  // denom = DtD @ C_old (bf16 MFMA, K=64); B-frags straight from global Cbt_o
  f32x4 accd[4][2];
#pragma unroll
  for (int mt = 0; mt < 4; ++mt)
#pragma unroll
    for (int nt = 0; nt < 2; ++nt) accd[mt][nt] = (f32x4){0.f, 0.f, 0.f, 0.f};
#pragma unroll
  for (int kc2 = 0; kc2 < 2; ++kc2) {
    bf16x8 cb[2], am[4];
#pragma unroll
    for (int nt = 0; nt < 2; ++nt)
      cb[nt] = *(const bf16x8*)(Cbt_o + ((size_t)b * N_ + ns + w * 32 + nt * 16 + ln) * R_ + kc2 * 32 + lg * 8);
#pragma unroll
    for (int mt = 0; mt < 4; ++mt) am[mt] = *(const bf16x8*)(dtd + (mt * 16 + ln) * 72 + kc2 * 32 + lg * 8);
#pragma unroll
    for (int mt = 0; mt < 4; ++mt)
#pragma unroll
      for (int nt = 0; nt < 2; ++nt)
        accd[mt][nt] = __builtin_amdgcn_mfma_f32_16x16x32_bf16(am[mt], cb[nt], accd[mt][nt], 0, 0, 0);
  }
  // update: C_new = C_old * acc / (accd + eps)
#pragma unroll
  for (int mt = 0; mt < 4; ++mt)
#pragma unroll
    for (int nt = 0; nt < 2; ++nt)
#pragma unroll
      for (int q = 0; q < 4; ++q) {
        int r = mt * 16 + lg * 4 + q;
        int n = w * 32 + nt * 16 + ln;
        size_t gi = ((size_t)b * R_ + r) * N_ + ns + n;
        float co = Cb_o[gi];
        float cn = co * acc[mt][nt][q] / (accd[mt][nt][q] + EPS_);
        Cb_n[gi] = cn;
        unsigned short h = f2bf(cn);
        crt[r * 136 + n] = (short)h;
        ctt[n * 72 + r] = (short)h;
      }
  __syncthreads();
#pragma unroll
  for (int j = 0; j < 4; ++j) {  // Cbf [64][128]
    int i = t + j * 256;
    int row = i >> 4, c = i & 15;
    *(int4*)(Cbf_n + ((size_t)b * R_ + row) * N_ + ns + c * 8) = *(const int4*)(crt + row * 136 + c * 8);
  }
#pragma unroll
  for (int j = 0; j < 4; ++j) {  // Cbt [128][64]
    int i = t + j * 256;
    int row = i >> 3, c = i & 7;
    *(int4*)(Cbt_n + ((size_t)b * N_ + ns + row) * R_ + c * 8) = *(const int4*)(ctt + row * 72 + c * 8);
  }
  // CCt partial gram of C_new (K = 128 local cols)
  f32x4 g[4];
#pragma unroll
  for (int nt = 0; nt < 4; ++nt) g[nt] = (f32x4){0.f, 0.f, 0.f, 0.f};
#pragma unroll
  for (int kc3 = 0; kc3 < 4; ++kc3) {
    bf16x8 a = *(const bf16x8*)(crt + (w * 16 + ln) * 136 + kc3 * 32 + lg * 8);
#pragma unroll
    for (int nt2 = 0; nt2 < 4; ++nt2) {
      bf16x8 bb = *(const bf16x8*)(crt + (nt2 * 16 + ln) * 136 + kc3 * 32 + lg * 8);
      g[nt2] = __builtin_amdgcn_mfma_f32_16x16x32_bf16(a, bb, g[nt2], 0, 0, 0);
    }
  }
  float* Po = CCtp_n + ((size_t)b * 16 + blockIdx.x) * 4096;
#pragma unroll
  for (int nt2 = 0; nt2 < 4; ++nt2)
#pragma unroll
    for (int q = 0; q < 4; ++q) Po[(w * 16 + lg * 4 + q) * 64 + nt2 * 16 + ln] = g[nt2][q];
}

// ============ fused: XC = x@Ct (K=2048 ksplit2-in-block), denom = D@CCt, D update, mirrors, DtD partial ============
// grid (DIM/64, B), 512 thr (8 waves: wq = w&3 output quarter, kh = w>>2 K-half)
__global__ __launch_bounds__(512, 4) void k_XD(
    const short* __restrict__ xbf, const short* __restrict__ Cbf_o, const float* __restrict__ Db_o,
    const short* __restrict__ Dbf_o, const float* __restrict__ CCtp_o, float* __restrict__ Db_n,
    short* __restrict__ Dbf_n, short* __restrict__ Dbt_n, float* __restrict__ DtDp_n) {
  const int b = blockIdx.y, d0 = blockIdx.x * 64;
  const int t = threadIdx.x;
  const int w = t >> 6, ln = t & 15, lg = (t & 63) >> 4;
  const int kh = w >> 2, wq = w & 3;
  __shared__ short stg[4][64 * 40];  // 0:x(kh0) 1:C(kh0) 2:x(kh1) 3:C(kh1)
  __shared__ float red[4 * 16 * 64];
  __shared__ short cct[64 * 72];
  __shared__ short dtt[64 * 72];
  f32x4 acc[4];
#pragma unroll
  for (int nt = 0; nt < 4; ++nt) acc[nt] = (f32x4){0.f, 0.f, 0.f, 0.f};
  const int tsel = t >> 7, tt = t & 127;
  const short* gsrc = (tsel & 1) ? (Cbf_o + (size_t)b * R_ * N_) : (xbf + ((size_t)b * DIM_ + d0) * N_);
  const int nbase = (tsel >> 1) * 1024;
  for (int cc = 0; cc < 32; ++cc) {
    __syncthreads();
    int4 v[2];
#pragma unroll
    for (int j = 0; j < 2; ++j) {
      int i = tt + j * 128;
      int row = i >> 2, c = i & 3;
      v[j] = *(const int4*)(gsrc + (size_t)row * N_ + nbase + cc * 32 + c * 8);
    }
#pragma unroll
    for (int j = 0; j < 2; ++j) {
      int i = tt + j * 128;
      int row = i >> 2, c = i & 3;
      *(int4*)(&stg[tsel][row * 40 + c * 8]) = v[j];
    }
    __syncthreads();
    bf16x8 a = *(const bf16x8*)(&stg[kh * 2][(wq * 16 + ln) * 40 + lg * 8]);
#pragma unroll
    for (int nt = 0; nt < 4; ++nt) {
      bf16x8 bb = *(const bf16x8*)(&stg[kh * 2 + 1][(nt * 16 + ln) * 40 + lg * 8]);
      acc[nt] = __builtin_amdgcn_mfma_f32_16x16x32_bf16(a, bb, acc[nt], 0, 0, 0);
    }
  }
  if (kh == 1) {
#pragma unroll
    for (int nt = 0; nt < 4; ++nt)
#pragma unroll
      for (int q = 0; q < 4; ++q) red[(wq * 16 + nt * 4 + q) * 64 + (t & 63)] = acc[nt][q];
  }
  {  // CCt partial sum -> bf16 LDS
    const float* P = CCtp_o + (size_t)b * 16 * 4096;
#pragma unroll
    for (int j = 0; j < 8; ++j) {
      int idx = t + j * 512;
      float s = 0.f;
#pragma unroll
      for (int ss = 0; ss < 16; ++ss) s += P[ss * 4096 + idx];
      cct[(idx >> 6) * 72 + (idx & 63)] = (short)f2bf(s);
    }
  }
  __syncthreads();
  if (kh == 0) {
#pragma unroll
    for (int nt = 0; nt < 4; ++nt)
#pragma unroll
      for (int q = 0; q < 4; ++q) acc[nt][q] += red[(wq * 16 + nt * 4 + q) * 64 + (t & 63)];
    f32x4 accd[4];
#pragma unroll
    for (int nt = 0; nt < 4; ++nt) accd[nt] = (f32x4){0.f, 0.f, 0.f, 0.f};
#pragma unroll
    for (int kc = 0; kc < 2; ++kc) {
      bf16x8 a = *(const bf16x8*)(Dbf_o + ((size_t)b * DIM_ + d0 + wq * 16 + ln) * R_ + kc * 32 + lg * 8);
#pragma unroll
      for (int nt = 0; nt < 4; ++nt) {
        bf16x8 bb = *(const bf16x8*)(cct + (nt * 16 + ln) * 72 + kc * 32 + lg * 8);
        accd[nt] = __builtin_amdgcn_mfma_f32_16x16x32_bf16(a, bb, accd[nt], 0, 0, 0);
      }
    }
#pragma unroll
    for (int nt = 0; nt < 4; ++nt)
#pragma unroll
      for (int q = 0; q < 4; ++q) {
        int dl = wq * 16 + lg * 4 + q;
        int r = nt * 16 + ln;
        size_t gi = ((size_t)b * DIM_ + d0 + dl) * R_ + r;
        float dold = Db_o[gi];
        float dn = dold * acc[nt][q] / (accd[nt][q] + EPS_);
        Db_n[gi] = dn;
        unsigned short h = f2bf(dn);
        Dbf_n[gi] = (short)h;
        dtt[r * 72 + dl] = (short)h;
      }
  }
  __syncthreads();
  {  // Dbt write-out [64 r][64 d] (all 8 waves)
    int row = t >> 3, c = t & 7;
    *(int4*)(Dbt_n + ((size_t)b * R_ + row) * DIM_ + d0 + c * 8) = *(const int4*)(dtt + row * 72 + c * 8);
  }
  if (kh == 0) {  // DtD partial gram (K = 64 local d)
    f32x4 g[4];
#pragma unroll
    for (int nt = 0; nt < 4; ++nt) g[nt] = (f32x4){0.f, 0.f, 0.f, 0.f};
#pragma unroll
    for (int kc = 0; kc < 2; ++kc) {
      bf16x8 a = *(const bf16x8*)(dtt + (wq * 16 + ln) * 72 + kc * 32 + lg * 8);
#pragma unroll
      for (int nt2 = 0; nt2 < 4; ++nt2) {
        bf16x8 bb = *(const bf16x8*)(dtt + (nt2 * 16 + ln) * 72 + kc * 32 + lg * 8);
        g[nt2] = __builtin_amdgcn_mfma_f32_16x16x32_bf16(a, bb, g[nt2], 0, 0, 0);
      }
    }
    float* Po = DtDp_n + ((size_t)b * 8 + blockIdx.x) * 4096;
#pragma unroll
    for (int nt2 = 0; nt2 < 4; ++nt2)
#pragma unroll
      for (int q = 0; q < 4; ++q) Po[(wq * 16 + lg * 4 + q) * 64 + nt2 * 16 + ln] = g[nt2][q];
  }
}

// ============ out[b,d,n] = sum_r Dbf[d,r] * Cbt[n,r]  (MFMA, K=64) ============
// grid (N/128, DIM/64, B), 256 thr
__global__ __launch_bounds__(256) void k_out(const short* __restrict__ Dbf, const short* __restrict__ Cbt,
                                             float* __restrict__ out) {
  const int b = blockIdx.z, d0 = blockIdx.y * 64, n0 = blockIdx.x * 128;
  const int t = threadIdx.x;
  const int w = t >> 6, ln = t & 15, lg = (t & 63) >> 4;
  __shared__ short ct[128 * 72];  // [n][r]
  __shared__ short dn[64 * 72];   // [d][r]
#pragma unroll
  for (int i = 0; i < 4; ++i) {
    int idx = i * 256 + t;
    int row = idx >> 3, c = idx & 7;
    *(int4*)(ct + row * 72 + c * 8) =
        *(const int4*)(Cbt + (size_t)b * N_ * R_ + (size_t)(n0 + row) * R_ + c * 8);
  }
#pragma unroll
  for (int i = 0; i < 2; ++i) {
    int idx = i * 256 + t;
    int row = idx >> 3, c = idx & 7;
    *(int4*)(dn + row * 72 + c * 8) =
        *(const int4*)(Dbf + (size_t)b * DIM_ * R_ + (size_t)(d0 + row) * R_ + c * 8);
  }
  __syncthreads();
  f32x4 acc[4][2];
#pragma unroll
  for (int mt = 0; mt < 4; ++mt)
#pragma unroll
    for (int nt = 0; nt < 2; ++nt) acc[mt][nt] = (f32x4){0.f, 0.f, 0.f, 0.f};
#pragma unroll
  for (int kc = 0; kc < 2; ++kc) {
    bf16x8 a[4], bb[2];
#pragma unroll
    for (int mt = 0; mt < 4; ++mt) a[mt] = *(const bf16x8*)(dn + (mt * 16 + ln) * 72 + kc * 32 + lg * 8);
#pragma unroll
    for (int nt = 0; nt < 2; ++nt)
      bb[nt] = *(const bf16x8*)(ct + (w * 32 + nt * 16 + ln) * 72 + kc * 32 + lg * 8);
#pragma unroll
    for (int mt = 0; mt < 4; ++mt)
#pragma unroll
      for (int nt = 0; nt < 2; ++nt)
        acc[mt][nt] = __builtin_amdgcn_mfma_f32_16x16x32_bf16(a[mt], bb[nt], acc[mt][nt], 0, 0, 0);
  }
  float* op = out + (size_t)b * DIM_ * N_;
#pragma unroll
  for (int mt = 0; mt < 4; ++mt)
#pragma unroll
    for (int nt = 0; nt < 2; ++nt) {
      int n = n0 + w * 32 + nt * 16 + ln;
#pragma unroll
      for (int q = 0; q < 4; ++q)
        op[(size_t)(d0 + mt * 16 + lg * 4 + q) * N_ + n] = acc[mt][nt][q];
    }
}

extern "C" void kernel_launch(void* const* d_in, const int* in_sizes, int n_in,
                              void* d_out, int out_size, void* d_ws, size_t ws_size,
                              hipStream_t stream) {
  const float* x = (const float*)d_in[0];
  const float* D = (const float*)d_in[1];
  const float* C = (const float*)d_in[2];
  float* out = (float*)d_out;

  // ---- ws (117.4 MB) ----
  char* wsb = (char*)d_ws;
  short* xbf   = (short*)(wsb);                // 67,108,864  relu(x) bf16 [b][d][n]
  float* Cb0   = (float*)(wsb + 67108864);     // 16,777,216
  short* Cbf0  = (short*)(wsb + 83886080);     //  8,388,608
  short* Cbt0  = (short*)(wsb + 92274688);     //  8,388,608
  float* Db0   = (float*)(wsb + 100663296);    //  4,194,304
  short* Dbf0  = (short*)(wsb + 104857600);    //  2,097,152
  short* Dbt0  = (short*)(wsb + 106954752);    //  2,097,152
  float* DtDp0 = (float*)(wsb + 109051904);    //  4,194,304  [b][8][64][64]
  float* DtDp1 = (float*)(wsb + 113246208);    //  4,194,304
  // ---- d_out overlay (125.8 MB of 134.2; k_out overwrites everything at the end) ----
  char* ob = (char*)d_out;
  short* xbt   = (short*)(ob);                 // 67,108,864  relu(x)^T bf16 [b][n][d]
  float* Cb1   = (float*)(ob + 67108864);      // 16,777,216
  short* Cbf1  = (short*)(ob + 83886080);      //  8,388,608
  short* Cbt1  = (short*)(ob + 92274688);      //  8,388,608
  float* Db1   = (float*)(ob + 100663296);     //  4,194,304
  short* Dbf1  = (short*)(ob + 104857600);     //  2,097,152
  short* Dbt1  = (short*)(ob + 106954752);     //  2,097,152
  float* CCtp0 = (float*)(ob + 109051904);     //  8,388,608  [b][16][64][64]
  float* CCtp1 = (float*)(ob + 117440512);     //  8,388,608

  float* CbS[2]   = {Cb0, Cb1};
  short* CbfS[2]  = {Cbf0, Cbf1};
  short* CbtS[2]  = {Cbt0, Cbt1};
  float* DbS[2]   = {Db0, Db1};
  short* DbfS[2]  = {Dbf0, Dbf1};
  short* DbtS[2]  = {Dbt0, Dbt1};
  float* DtDpS[2] = {DtDp0, DtDp1};
  float* CCtpS[2] = {CCtp0, CCtp1};

  k_xprep<<<dim3(N_ / 64, DIM_ / 64, B_), 256, 0, stream>>>(x, xbf, xbt);
  k_bcastD<<<dim3(8, B_), 256, 0, stream>>>(D, Db0, Dbf0, Dbt0, DtDp0);
  k_bcastC<<<dim3(16, B_), 256, 0, stream>>>(C, Cb0, Cbf0, Cbt0, CCtp0);

  for (int k = 0; k < K_; ++k) {
    int p = k & 1, q = 1 - p;
    k_AC<<<dim3(16, B_), 256, 0, stream>>>(xbt, DbtS[p], CbS[p], CbtS[p], DtDpS[p],
                                           CbS[q], CbfS[q], CbtS[q], CCtpS[q]);
    k_XD<<<dim3(8, B_), 512, 0, stream>>>(xbf, CbfS[p], DbS[p], DbfS[p], CCtpS[p],
                                          DbS[q], DbfS[q], DbtS[q], DtDpS[q]);
  }
  // 6 iterations end with state in set 0 (both live in ws)
  k_out<<<dim3(N_ / 128, DIM_ / 64, B_), 256, 0, stream>>>(Dbf0, Cbt0, out);
}